// Round 7
// baseline (8871.252 us; speedup 1.0000x reference)
//
#include <hip/hip_runtime.h>

#define NPTS 16384
#define NSEED 4096
#define KNB 32
#define TOTROWS (NSEED*KNB)   // 131072
#define FPS_T 512

typedef float f32x4 __attribute__((ext_vector_type(4)));
typedef short s16x8 __attribute__((ext_vector_type(8)));

__device__ __forceinline__ unsigned short f2bf(float f){
    unsigned int u = __float_as_uint(f);
    u = (u + 0x7FFFu + ((u >> 16) & 1u)) >> 16;
    return (unsigned short)u;
}

// ---------------- prep: pp = |p|^2, transpose+bf16 weights ----------------
__global__ void prep_kernel(const float* __restrict__ pos,
                            const float* __restrict__ w1b,
                            const float* __restrict__ w2a,
                            const float* __restrict__ w2b,
                            float* __restrict__ pp,
                            unsigned short* __restrict__ w1bT,
                            unsigned short* __restrict__ w2aT,
                            unsigned short* __restrict__ w2bT){
    int i = blockIdx.x*blockDim.x + threadIdx.x;
    int stride = gridDim.x*blockDim.x;
    for (int j=i;j<NPTS;j+=stride){
        float x=pos[3*j], y=pos[3*j+1], z=pos[3*j+2];
        pp[j] = __fadd_rn(__fadd_rn(__fmul_rn(x,x),__fmul_rn(y,y)),__fmul_rn(z,z));
    }
    for (int e=i;e<256*128;e+=stride){ int n=e>>7,k=e&127; w1bT[e]=f2bf(w1b[k*256+n]); }
    for (int e=i;e<512*512;e+=stride){ int n=e>>9,k=e&511; w2aT[e]=f2bf(w2a[k*512+n]); }
    for (int e=i;e<384*512;e+=stride){ int n=e>>9,k=e&511; w2bT[e]=f2bf(w2b[k*384+n]); }
}

// ---------------- FPS: single block, 512 threads, 32 pts/thread -----------
// NO ARRAYS: 128 named scalars (macro-generated). r4-r6 showed any float[32]
// alloca ends in scratch (VGPR=88, ~100MB FETCH, 2.05us/iter); named locals
// are SSA values from the frontend and cannot be demoted.
#define REP32(X) X(0)X(1)X(2)X(3)X(4)X(5)X(6)X(7)X(8)X(9)X(10)X(11)X(12)X(13)X(14)X(15)X(16)X(17)X(18)X(19)X(20)X(21)X(22)X(23)X(24)X(25)X(26)X(27)X(28)X(29)X(30)X(31)

__global__ __launch_bounds__(FPS_T,2) void fps_kernel(const float* __restrict__ pos,
                                                      int* __restrict__ seed_idx,
                                                      float* __restrict__ seeds){
    __shared__ float2 slot[2][FPS_T/64];
    const int t = threadIdx.x;
    const int lane = t&63, wv = t>>6;
#define FPS_DECL(r) float px##r,py##r,pz##r,dd##r;
    REP32(FPS_DECL)
#define FPS_INIT(r) { const int j=t+((r)<<9); px##r=pos[3*j]; py##r=pos[3*j+1]; pz##r=pos[3*j+2]; dd##r=__builtin_inff(); }
    REP32(FPS_INIT)
    if (t==0){
        seed_idx[0]=0;
        seeds[0]=pos[0]; seeds[1]=pos[1]; seeds[2]=pos[2];
    }
    float lx=pos[0], ly=pos[1], lz=pos[2];
    for (int i=1;i<NSEED;i++){
        float best=-1.0f; int bj=0x7fffffff;
        // match numpy per-op IEEE (no contraction): ((dx^2+dy^2)+dz^2);
        // ascending r => ascending j, strict > keeps first max (np.argmax).
#define FPS_DIST(r) { \
        float dx=__fsub_rn(px##r,lx); \
        float dy=__fsub_rn(py##r,ly); \
        float dz=__fsub_rn(pz##r,lz); \
        float d=__fadd_rn(__fadd_rn(__fmul_rn(dx,dx),__fmul_rn(dy,dy)),__fmul_rn(dz,dz)); \
        float nd=fminf(dd##r,d); \
        dd##r=nd; \
        if (nd>best){ best=nd; bj=t+((r)<<9); } }
        REP32(FPS_DIST)
#pragma unroll
        for (int off=1;off<64;off<<=1){
            float ov=__shfl_xor(best,off);
            int   oj=__shfl_xor(bj,off);
            if (ov>best || (ov==best && oj<bj)){ best=ov; bj=oj; }
        }
        const int par=i&1;
        if (lane==0) slot[par][wv]=make_float2(best,(float)bj);  // bj<2^24 exact
        __syncthreads();
        float gv=slot[par][0].x, gjf=slot[par][0].y;
#pragma unroll
        for (int w=1;w<FPS_T/64;w++){
            float2 s=slot[par][w];
            if (s.x>gv || (s.x==gv && s.y<gjf)){ gv=s.x; gjf=s.y; }
        }
        const int jwin=(int)gjf;
        lx=pos[3*jwin]; ly=pos[3*jwin+1]; lz=pos[3*jwin+2];   // broadcast load
        if (t==0){ seed_idx[i]=jwin; seeds[3*i]=lx; seeds[3*i+1]=ly; seeds[3*i+2]=lz; }
    }
}

// ---------------- KNN: one wave per seed, sorted 32-list in lanes 0..31 ----
__global__ __launch_bounds__(256) void knn_kernel(const float* __restrict__ pos,
                                                  const float* __restrict__ pp,
                                                  const float* __restrict__ seeds,
                                                  float* __restrict__ rel){
    const int lane = threadIdx.x & 63;
    const int s = blockIdx.x*4 + (threadIdx.x>>6);
    const float sx=seeds[3*s], sy=seeds[3*s+1], sz=seeds[3*s+2];
    const float ss = __fadd_rn(__fadd_rn(__fmul_rn(sx,sx),__fmul_rn(sy,sy)),__fmul_rn(sz,sz));
    const float s2x=__fmul_rn(2.0f,sx), s2y=__fmul_rn(2.0f,sy), s2z=__fmul_rn(2.0f,sz);
    float lv=__builtin_inff(); int li=0;
    float curmax=__builtin_inff();
    for (int c=0;c<NPTS/64;c++){
        const int j=(c<<6)+lane;
        float x=pos[3*j], y=pos[3*j+1], z=pos[3*j+2];
        float dot=__fmul_rn(s2x,x);
        dot=fmaf(s2y,y,dot);
        dot=fmaf(s2z,z,dot);
        float d2=__fsub_rn(__fadd_rn(ss,pp[j]),dot);   // (ss+pp) - (2s)·p
        unsigned long long m=__ballot(d2<curmax);
        while (m){
            int src=__builtin_ctzll(m);
            m&=m-1;
            float bv=__shfl(d2,src);
            if (bv<curmax){
                int bjj=(c<<6)+src;
                float upv=__shfl_up(lv,1);
                int   upi=__shfl_up(li,1);
                bool keep=(lv<=bv);                    // equal keeps earlier (lower) index
                bool upless=(upv<=bv)||(lane==0);
                lv = keep?lv:(upless?bv:upv);
                li = keep?li:(upless?bjj:upi);
                curmax=__shfl(lv,31);
            }
        }
    }
    if (lane<KNB){
        int nb=li;
        float* o=&rel[(size_t)(s*KNB+lane)*3];
        o[0]=__fsub_rn(pos[3*nb],sx);
        o[1]=__fsub_rn(pos[3*nb+1],sy);
        o[2]=__fsub_rn(pos[3*nb+2],sz);
    }
}

// ---------------- MLP1: Lin(3->128)+BN+ReLU (VALU), Lin(128->256) (MFMA), pool
__global__ __launch_bounds__(256,2) void mlp1_kernel(const float* __restrict__ rel,
    const float* __restrict__ w1a, const float* __restrict__ b1a,
    const float* __restrict__ g1, const float* __restrict__ be1,
    const float* __restrict__ mu1, const float* __restrict__ var1,
    const unsigned short* __restrict__ w1bT, const float* __restrict__ b1b,
    unsigned short* __restrict__ hbuf, unsigned short* __restrict__ hmaxb,
    int rowBase){
    __shared__ __align__(16) unsigned short h1[256][136];   // 128 + 8 pad
    const int t=threadIdx.x;
    const int lrow = blockIdx.x*256 + t;
    const int grow = rowBase + lrow;
    {
        const float x0=rel[3*(size_t)grow], x1=rel[3*(size_t)grow+1], x2=rel[3*(size_t)grow+2];
#pragma unroll 4
        for (int c=0;c<128;c++){
            float v=__fmul_rn(x0,w1a[c]);
            v=fmaf(x1,w1a[128+c],v);
            v=fmaf(x2,w1a[256+c],v);
            v=__fadd_rn(v,b1a[c]);
            float rs=1.0f/__fsqrt_rn(__fadd_rn(var1[c],1e-5f));
            v=__fadd_rn(__fmul_rn(__fmul_rn(__fsub_rn(v,mu1[c]),rs),g1[c]),be1[c]);
            v=fmaxf(v,0.0f);
            h1[t][c]=f2bf(v);
        }
    }
    __syncthreads();
    const int lane=t&63, wv=t>>6;
    const int m=lane&15, kg=lane>>4;
    const int r0=wv*64;
#pragma unroll 1
    for (int nc=0;nc<4;nc++){
        f32x4 acc[4][4];
#pragma unroll
        for (int nt=0;nt<4;nt++){
            float bi=b1b[nc*64+nt*16+m];
            f32x4 vv={bi,bi,bi,bi};
#pragma unroll
            for (int mt=0;mt<4;mt++) acc[mt][nt]=vv;
        }
#pragma unroll
        for (int ks=0;ks<4;ks++){
            s16x8 a[4],b[4];
#pragma unroll
            for (int mt=0;mt<4;mt++)
                a[mt]=*(const s16x8*)&h1[r0+mt*16+m][ks*32+kg*8];
#pragma unroll
            for (int nt=0;nt<4;nt++)
                b[nt]=*(const s16x8*)&w1bT[(size_t)(nc*64+nt*16+m)*128 + ks*32+kg*8];
#pragma unroll
            for (int mt=0;mt<4;mt++)
#pragma unroll
                for (int nt=0;nt<4;nt++)
                    acc[mt][nt]=__builtin_amdgcn_mfma_f32_16x16x32_bf16(a[mt],b[nt],acc[mt][nt],0,0,0);
        }
#pragma unroll
        for (int nt=0;nt<4;nt++){
            float pA=-__builtin_inff(), pB=-__builtin_inff();
#pragma unroll
            for (int mt=0;mt<4;mt++){
#pragma unroll
                for (int rg=0;rg<4;rg++){
                    float v=acc[mt][nt][rg];
                    int lr = blockIdx.x*256 + r0 + mt*16 + kg*4 + rg;
                    hbuf[(size_t)lr*256 + nc*64+nt*16+m]=f2bf(v);
                    if (mt<2) pA=fmaxf(pA,v); else pB=fmaxf(pB,v);
                }
            }
            pA=fmaxf(pA,__shfl_xor(pA,16)); pA=fmaxf(pA,__shfl_xor(pA,32));
            pB=fmaxf(pB,__shfl_xor(pB,16)); pB=fmaxf(pB,__shfl_xor(pB,32));
            if (lane<16){
                int sA=(rowBase + blockIdx.x*256 + r0)>>5;
                hmaxb[(size_t)sA*256 + nc*64+nt*16+m]=f2bf(pA);
                hmaxb[(size_t)(sA+1)*256 + nc*64+nt*16+m]=f2bf(pB);
            }
        }
    }
}

// ---------------- MLP2: [hmax|h](512) @ w2a + b2a -> BN -> ReLU -> g -------
__global__ __launch_bounds__(256,2) void mlp2_kernel(const unsigned short* __restrict__ hbuf,
    const unsigned short* __restrict__ hmaxb, const unsigned short* __restrict__ w2aT,
    const float* __restrict__ b2a, const float* __restrict__ g2, const float* __restrict__ be2,
    const float* __restrict__ mu2, const float* __restrict__ var2,
    unsigned short* __restrict__ gbuf, int rowBase){
    __shared__ __align__(16) unsigned short at[64][520];    // 512 + 8 pad
    const int t=threadIdx.x;
    const int br = blockIdx.x*64;
    {
        const int lr=t>>2, q=t&3;
        const s16x8* srcH=(const s16x8*)&hbuf[((size_t)(br+lr))*256 + q*64];
        s16x8* dstH=(s16x8*)&at[lr][256+q*64];
        const int sd=(rowBase+br+lr)>>5;
        const s16x8* srcM=(const s16x8*)&hmaxb[(size_t)sd*256 + q*64];
        s16x8* dstM=(s16x8*)&at[lr][q*64];
#pragma unroll
        for (int u=0;u<8;u++){ dstH[u]=srcH[u]; dstM[u]=srcM[u]; }
    }
    __syncthreads();
    const int lane=t&63, wv=t>>6;
    const int m=lane&15, kg=lane>>4;
    const int n0=wv*128;
    f32x4 acc[4][8];
#pragma unroll
    for (int nt=0;nt<8;nt++){
        float bi=b2a[n0+nt*16+m];
        f32x4 vv={bi,bi,bi,bi};
#pragma unroll
        for (int mt=0;mt<4;mt++) acc[mt][nt]=vv;
    }
#pragma unroll 2
    for (int ks=0;ks<16;ks++){
        s16x8 a[4],b[8];
#pragma unroll
        for (int mt=0;mt<4;mt++) a[mt]=*(const s16x8*)&at[mt*16+m][ks*32+kg*8];
#pragma unroll
        for (int nt=0;nt<8;nt++) b[nt]=*(const s16x8*)&w2aT[(size_t)(n0+nt*16+m)*512 + ks*32+kg*8];
#pragma unroll
        for (int mt=0;mt<4;mt++)
#pragma unroll
            for (int nt=0;nt<8;nt++)
                acc[mt][nt]=__builtin_amdgcn_mfma_f32_16x16x32_bf16(a[mt],b[nt],acc[mt][nt],0,0,0);
    }
#pragma unroll
    for (int nt=0;nt<8;nt++){
        const int n=n0+nt*16+m;
        const float rs=1.0f/__fsqrt_rn(__fadd_rn(var2[n],1e-5f));
        const float mu=mu2[n], gg=g2[n], bb=be2[n];
#pragma unroll
        for (int mt=0;mt<4;mt++){
#pragma unroll
            for (int rg=0;rg<4;rg++){
                float v=acc[mt][nt][rg];
                v=__fadd_rn(__fmul_rn(__fmul_rn(__fsub_rn(v,mu),rs),gg),bb);
                v=fmaxf(v,0.0f);
                const int lr=br+mt*16+kg*4+rg;
                gbuf[(size_t)lr*512+n]=f2bf(v);
            }
        }
    }
}

// ---------------- MLP3: g @ w2b + b2b -> per-seed max over 32 rows -> out --
// NOTE: d_out is float32 (reference output dtype).
__global__ __launch_bounds__(256,2) void mlp3_kernel(const unsigned short* __restrict__ gbuf,
    const unsigned short* __restrict__ w2bT, const float* __restrict__ b2b,
    float* __restrict__ outp, int rowBase){
    __shared__ __align__(16) unsigned short at[64][520];
    const int t=threadIdx.x;
    const int br=blockIdx.x*64;
    {
        const int lr=t>>2,q=t&3;
        const s16x8* src=(const s16x8*)&gbuf[((size_t)(br+lr))*512+q*128];
        s16x8* dst=(s16x8*)&at[lr][q*128];
#pragma unroll
        for (int u=0;u<16;u++) dst[u]=src[u];
    }
    __syncthreads();
    const int lane=t&63, wv=t>>6;
    const int m=lane&15, kg=lane>>4;
    const int n0=wv*96;
    f32x4 acc[4][6];
#pragma unroll
    for (int nt=0;nt<6;nt++){
        float bi=b2b[n0+nt*16+m];
        f32x4 vv={bi,bi,bi,bi};
#pragma unroll
        for (int mt=0;mt<4;mt++) acc[mt][nt]=vv;
    }
#pragma unroll 2
    for (int ks=0;ks<16;ks++){
        s16x8 a[4],b[6];
#pragma unroll
        for (int mt=0;mt<4;mt++) a[mt]=*(const s16x8*)&at[mt*16+m][ks*32+kg*8];
#pragma unroll
        for (int nt=0;nt<6;nt++) b[nt]=*(const s16x8*)&w2bT[(size_t)(n0+nt*16+m)*512+ks*32+kg*8];
#pragma unroll
        for (int mt=0;mt<4;mt++)
#pragma unroll
            for (int nt=0;nt<6;nt++)
                acc[mt][nt]=__builtin_amdgcn_mfma_f32_16x16x32_bf16(a[mt],b[nt],acc[mt][nt],0,0,0);
    }
    const int sA=(rowBase+br)>>5;
#pragma unroll
    for (int nt=0;nt<6;nt++){
        float pA=-__builtin_inff(), pB=-__builtin_inff();
#pragma unroll
        for (int mt=0;mt<4;mt++){
#pragma unroll
            for (int rg=0;rg<4;rg++){
                float v=acc[mt][nt][rg];
                if (mt<2) pA=fmaxf(pA,v); else pB=fmaxf(pB,v);
            }
        }
        pA=fmaxf(pA,__shfl_xor(pA,16)); pA=fmaxf(pA,__shfl_xor(pA,32));
        pB=fmaxf(pB,__shfl_xor(pB,16)); pB=fmaxf(pB,__shfl_xor(pB,32));
        if (lane<16){
            outp[(size_t)sA*384 + n0+nt*16+m]=pA;
            outp[(size_t)(sA+1)*384 + n0+nt*16+m]=pB;
        }
    }
}

extern "C" void kernel_launch(void* const* d_in, const int* in_sizes, int n_in,
                              void* d_out, int out_size, void* d_ws, size_t ws_size,
                              hipStream_t stream) {
    const float* pos =(const float*)d_in[0];
    // d_in[1] = batch (int64), unused (single graph)
    const float* w1a =(const float*)d_in[2];
    const float* b1a =(const float*)d_in[3];
    const float* g1  =(const float*)d_in[4];
    const float* be1 =(const float*)d_in[5];
    const float* mu1 =(const float*)d_in[6];
    const float* var1=(const float*)d_in[7];
    const float* w1b =(const float*)d_in[8];
    const float* b1b =(const float*)d_in[9];
    const float* w2a =(const float*)d_in[10];
    const float* b2a =(const float*)d_in[11];
    const float* g2  =(const float*)d_in[12];
    const float* be2 =(const float*)d_in[13];
    const float* mu2 =(const float*)d_in[14];
    const float* var2=(const float*)d_in[15];
    const float* w2b =(const float*)d_in[16];
    const float* b2b =(const float*)d_in[17];

    char* base=(char*)d_ws;
    size_t off=0;
    auto alloc=[&](size_t bytes)->void*{
        void* p=base+off; off=(off+bytes+255)&~(size_t)255; return p;
    };
    int*   seed_idx=(int*)  alloc((size_t)NSEED*4);
    float* seeds   =(float*)alloc((size_t)NSEED*3*4);
    float* pp      =(float*)alloc((size_t)NPTS*4);
    float* rel     =(float*)alloc((size_t)TOTROWS*3*4);
    unsigned short* hmaxb=(unsigned short*)alloc((size_t)NSEED*256*2);
    unsigned short* w1bT =(unsigned short*)alloc((size_t)256*128*2);
    unsigned short* w2aT =(unsigned short*)alloc((size_t)512*512*2);
    unsigned short* w2bT =(unsigned short*)alloc((size_t)384*512*2);
    size_t fixed=off;

    // pick the fewest chunks whose h/g scratch fits ws_size
    int nch=512;
    for (int c=1;c<=512;c*=2){
        size_t need=fixed + (size_t)(TOTROWS/c)*(256*2 + 512*2) + 1024;
        if (need<=ws_size){ nch=c; break; }
    }
    const int chunkRows=TOTROWS/nch;            // multiple of 256 for c<=512
    unsigned short* hbuf=(unsigned short*)alloc((size_t)chunkRows*256*2);
    unsigned short* gbuf=(unsigned short*)alloc((size_t)chunkRows*512*2);

    prep_kernel<<<256,256,0,stream>>>(pos,w1b,w2a,w2b,pp,w1bT,w2aT,w2bT);
    fps_kernel<<<1,FPS_T,0,stream>>>(pos,seed_idx,seeds);
    knn_kernel<<<NSEED/4,256,0,stream>>>(pos,pp,seeds,rel);
    for (int c=0;c<nch;c++){
        const int rowBase=c*chunkRows;
        mlp1_kernel<<<chunkRows/256,256,0,stream>>>(rel,w1a,b1a,g1,be1,mu1,var1,w1bT,b1b,hbuf,hmaxb,rowBase);
        mlp2_kernel<<<chunkRows/64,256,0,stream>>>(hbuf,hmaxb,w2aT,b2a,g2,be2,mu2,var2,gbuf,rowBase);
        mlp3_kernel<<<chunkRows/64,256,0,stream>>>(gbuf,w2bT,b2b,(float*)d_out,rowBase);
    }
}

// Round 8
// 8823.702 us; speedup vs baseline: 1.0054x; 1.0054x over previous
//
#include <hip/hip_runtime.h>

#define NPTS 16384
#define NSEED 4096
#define KNB 32
#define TOTROWS (NSEED*KNB)   // 131072
#define FPS_T 512

typedef float f32x4 __attribute__((ext_vector_type(4)));
typedef short s16x8 __attribute__((ext_vector_type(8)));

__device__ __forceinline__ unsigned short f2bf(float f){
    unsigned int u = __float_as_uint(f);
    u = (u + 0x7FFFu + ((u >> 16) & 1u)) >> 16;
    return (unsigned short)u;
}

// ---------------- prep: pp = |p|^2, transpose+bf16 weights ----------------
__global__ void prep_kernel(const float* __restrict__ pos,
                            const float* __restrict__ w1b,
                            const float* __restrict__ w2a,
                            const float* __restrict__ w2b,
                            float* __restrict__ pp,
                            unsigned short* __restrict__ w1bT,
                            unsigned short* __restrict__ w2aT,
                            unsigned short* __restrict__ w2bT){
    int i = blockIdx.x*blockDim.x + threadIdx.x;
    int stride = gridDim.x*blockDim.x;
    for (int j=i;j<NPTS;j+=stride){
        float x=pos[3*j], y=pos[3*j+1], z=pos[3*j+2];
        pp[j] = __fadd_rn(__fadd_rn(__fmul_rn(x,x),__fmul_rn(y,y)),__fmul_rn(z,z));
    }
    for (int e=i;e<256*128;e+=stride){ int n=e>>7,k=e&127; w1bT[e]=f2bf(w1b[k*256+n]); }
    for (int e=i;e<512*512;e+=stride){ int n=e>>9,k=e&511; w2aT[e]=f2bf(w2a[k*512+n]); }
    for (int e=i;e<384*512;e+=stride){ int n=e>>9,k=e&511; w2bT[e]=f2bf(w2b[k*384+n]); }
}

// ---------------- FPS: single block, 512 threads, 32 pts/thread -----------
// r4-r7 forensics: coords are loop-invariant loads from a __restrict__ const
// pointer -> LLVM sinks/remats them INTO the loop (VGPR=88, ~100MB refetch,
// 2.04us/iter) regardless of array vs named-scalar form. Fix: pin each value
// in a VGPR with an opaque empty inline-asm ("+v") after init — asm outputs
// are not rematerializable, so the 96 coords stay register-resident.
#define REP32(X) X(0)X(1)X(2)X(3)X(4)X(5)X(6)X(7)X(8)X(9)X(10)X(11)X(12)X(13)X(14)X(15)X(16)X(17)X(18)X(19)X(20)X(21)X(22)X(23)X(24)X(25)X(26)X(27)X(28)X(29)X(30)X(31)

__global__ __launch_bounds__(FPS_T,2) void fps_kernel(const float* __restrict__ pos,
                                                      int* __restrict__ seed_idx,
                                                      float* __restrict__ seeds){
    __shared__ float2 slot[2][FPS_T/64];
    const int t = threadIdx.x;
    const int lane = t&63, wv = t>>6;
#define FPS_DECL(r) float px##r,py##r,pz##r,dd##r;
    REP32(FPS_DECL)
#define FPS_INIT(r) { const int j=t+((r)<<9); px##r=pos[3*j]; py##r=pos[3*j+1]; pz##r=pos[3*j+2]; dd##r=__builtin_inff(); }
    REP32(FPS_INIT)
#define FPS_PIN(r) asm volatile("" : "+v"(px##r), "+v"(py##r), "+v"(pz##r));
    REP32(FPS_PIN)
    if (t==0){
        seed_idx[0]=0;
        seeds[0]=pos[0]; seeds[1]=pos[1]; seeds[2]=pos[2];
    }
    float lx=pos[0], ly=pos[1], lz=pos[2];
    for (int i=1;i<NSEED;i++){
        float best=-1.0f; int bj=0x7fffffff;
        // match numpy per-op IEEE (no contraction): ((dx^2+dy^2)+dz^2);
        // ascending r => ascending j, strict > keeps first max (np.argmax).
#define FPS_DIST(r) { \
        float dx=__fsub_rn(px##r,lx); \
        float dy=__fsub_rn(py##r,ly); \
        float dz=__fsub_rn(pz##r,lz); \
        float d=__fadd_rn(__fadd_rn(__fmul_rn(dx,dx),__fmul_rn(dy,dy)),__fmul_rn(dz,dz)); \
        float nd=fminf(dd##r,d); \
        dd##r=nd; \
        if (nd>best){ best=nd; bj=t+((r)<<9); } }
        REP32(FPS_DIST)
#pragma unroll
        for (int off=1;off<64;off<<=1){
            float ov=__shfl_xor(best,off);
            int   oj=__shfl_xor(bj,off);
            if (ov>best || (ov==best && oj<bj)){ best=ov; bj=oj; }
        }
        const int par=i&1;
        if (lane==0) slot[par][wv]=make_float2(best,(float)bj);  // bj<2^24 exact
        __syncthreads();
        float gv=slot[par][0].x, gjf=slot[par][0].y;
#pragma unroll
        for (int w=1;w<FPS_T/64;w++){
            float2 s=slot[par][w];
            if (s.x>gv || (s.x==gv && s.y<gjf)){ gv=s.x; gjf=s.y; }
        }
        const int jwin=(int)gjf;
        lx=pos[3*jwin]; ly=pos[3*jwin+1]; lz=pos[3*jwin+2];   // broadcast load
        if (t==0){ seed_idx[i]=jwin; seeds[3*i]=lx; seeds[3*i+1]=ly; seeds[3*i+2]=lz; }
    }
}

// ---------------- KNN: one wave per seed, sorted 32-list in lanes 0..31 ----
__global__ __launch_bounds__(256) void knn_kernel(const float* __restrict__ pos,
                                                  const float* __restrict__ pp,
                                                  const float* __restrict__ seeds,
                                                  float* __restrict__ rel){
    const int lane = threadIdx.x & 63;
    const int s = blockIdx.x*4 + (threadIdx.x>>6);
    const float sx=seeds[3*s], sy=seeds[3*s+1], sz=seeds[3*s+2];
    const float ss = __fadd_rn(__fadd_rn(__fmul_rn(sx,sx),__fmul_rn(sy,sy)),__fmul_rn(sz,sz));
    const float s2x=__fmul_rn(2.0f,sx), s2y=__fmul_rn(2.0f,sy), s2z=__fmul_rn(2.0f,sz);
    float lv=__builtin_inff(); int li=0;
    float curmax=__builtin_inff();
    for (int c=0;c<NPTS/64;c++){
        const int j=(c<<6)+lane;
        float x=pos[3*j], y=pos[3*j+1], z=pos[3*j+2];
        float dot=__fmul_rn(s2x,x);
        dot=fmaf(s2y,y,dot);
        dot=fmaf(s2z,z,dot);
        float d2=__fsub_rn(__fadd_rn(ss,pp[j]),dot);   // (ss+pp) - (2s)·p
        unsigned long long m=__ballot(d2<curmax);
        while (m){
            int src=__builtin_ctzll(m);
            m&=m-1;
            float bv=__shfl(d2,src);
            if (bv<curmax){
                int bjj=(c<<6)+src;
                float upv=__shfl_up(lv,1);
                int   upi=__shfl_up(li,1);
                bool keep=(lv<=bv);                    // equal keeps earlier (lower) index
                bool upless=(upv<=bv)||(lane==0);
                lv = keep?lv:(upless?bv:upv);
                li = keep?li:(upless?bjj:upi);
                curmax=__shfl(lv,31);
            }
        }
    }
    if (lane<KNB){
        int nb=li;
        float* o=&rel[(size_t)(s*KNB+lane)*3];
        o[0]=__fsub_rn(pos[3*nb],sx);
        o[1]=__fsub_rn(pos[3*nb+1],sy);
        o[2]=__fsub_rn(pos[3*nb+2],sz);
    }
}

// ---------------- MLP1: Lin(3->128)+BN+ReLU (VALU), Lin(128->256) (MFMA), pool
__global__ __launch_bounds__(256,2) void mlp1_kernel(const float* __restrict__ rel,
    const float* __restrict__ w1a, const float* __restrict__ b1a,
    const float* __restrict__ g1, const float* __restrict__ be1,
    const float* __restrict__ mu1, const float* __restrict__ var1,
    const unsigned short* __restrict__ w1bT, const float* __restrict__ b1b,
    unsigned short* __restrict__ hbuf, unsigned short* __restrict__ hmaxb,
    int rowBase){
    __shared__ __align__(16) unsigned short h1[256][136];   // 128 + 8 pad
    const int t=threadIdx.x;
    const int lrow = blockIdx.x*256 + t;
    const int grow = rowBase + lrow;
    {
        const float x0=rel[3*(size_t)grow], x1=rel[3*(size_t)grow+1], x2=rel[3*(size_t)grow+2];
#pragma unroll 4
        for (int c=0;c<128;c++){
            float v=__fmul_rn(x0,w1a[c]);
            v=fmaf(x1,w1a[128+c],v);
            v=fmaf(x2,w1a[256+c],v);
            v=__fadd_rn(v,b1a[c]);
            float rs=1.0f/__fsqrt_rn(__fadd_rn(var1[c],1e-5f));
            v=__fadd_rn(__fmul_rn(__fmul_rn(__fsub_rn(v,mu1[c]),rs),g1[c]),be1[c]);
            v=fmaxf(v,0.0f);
            h1[t][c]=f2bf(v);
        }
    }
    __syncthreads();
    const int lane=t&63, wv=t>>6;
    const int m=lane&15, kg=lane>>4;
    const int r0=wv*64;
#pragma unroll 1
    for (int nc=0;nc<4;nc++){
        f32x4 acc[4][4];
#pragma unroll
        for (int nt=0;nt<4;nt++){
            float bi=b1b[nc*64+nt*16+m];
            f32x4 vv={bi,bi,bi,bi};
#pragma unroll
            for (int mt=0;mt<4;mt++) acc[mt][nt]=vv;
        }
#pragma unroll
        for (int ks=0;ks<4;ks++){
            s16x8 a[4],b[4];
#pragma unroll
            for (int mt=0;mt<4;mt++)
                a[mt]=*(const s16x8*)&h1[r0+mt*16+m][ks*32+kg*8];
#pragma unroll
            for (int nt=0;nt<4;nt++)
                b[nt]=*(const s16x8*)&w1bT[(size_t)(nc*64+nt*16+m)*128 + ks*32+kg*8];
#pragma unroll
            for (int mt=0;mt<4;mt++)
#pragma unroll
                for (int nt=0;nt<4;nt++)
                    acc[mt][nt]=__builtin_amdgcn_mfma_f32_16x16x32_bf16(a[mt],b[nt],acc[mt][nt],0,0,0);
        }
#pragma unroll
        for (int nt=0;nt<4;nt++){
            float pA=-__builtin_inff(), pB=-__builtin_inff();
#pragma unroll
            for (int mt=0;mt<4;mt++){
#pragma unroll
                for (int rg=0;rg<4;rg++){
                    float v=acc[mt][nt][rg];
                    int lr = blockIdx.x*256 + r0 + mt*16 + kg*4 + rg;
                    hbuf[(size_t)lr*256 + nc*64+nt*16+m]=f2bf(v);
                    if (mt<2) pA=fmaxf(pA,v); else pB=fmaxf(pB,v);
                }
            }
            pA=fmaxf(pA,__shfl_xor(pA,16)); pA=fmaxf(pA,__shfl_xor(pA,32));
            pB=fmaxf(pB,__shfl_xor(pB,16)); pB=fmaxf(pB,__shfl_xor(pB,32));
            if (lane<16){
                int sA=(rowBase + blockIdx.x*256 + r0)>>5;
                hmaxb[(size_t)sA*256 + nc*64+nt*16+m]=f2bf(pA);
                hmaxb[(size_t)(sA+1)*256 + nc*64+nt*16+m]=f2bf(pB);
            }
        }
    }
}

// ---------------- MLP2: [hmax|h](512) @ w2a + b2a -> BN -> ReLU -> g -------
__global__ __launch_bounds__(256,2) void mlp2_kernel(const unsigned short* __restrict__ hbuf,
    const unsigned short* __restrict__ hmaxb, const unsigned short* __restrict__ w2aT,
    const float* __restrict__ b2a, const float* __restrict__ g2, const float* __restrict__ be2,
    const float* __restrict__ mu2, const float* __restrict__ var2,
    unsigned short* __restrict__ gbuf, int rowBase){
    __shared__ __align__(16) unsigned short at[64][520];    // 512 + 8 pad
    const int t=threadIdx.x;
    const int br = blockIdx.x*64;
    {
        const int lr=t>>2, q=t&3;
        const s16x8* srcH=(const s16x8*)&hbuf[((size_t)(br+lr))*256 + q*64];
        s16x8* dstH=(s16x8*)&at[lr][256+q*64];
        const int sd=(rowBase+br+lr)>>5;
        const s16x8* srcM=(const s16x8*)&hmaxb[(size_t)sd*256 + q*64];
        s16x8* dstM=(s16x8*)&at[lr][q*64];
#pragma unroll
        for (int u=0;u<8;u++){ dstH[u]=srcH[u]; dstM[u]=srcM[u]; }
    }
    __syncthreads();
    const int lane=t&63, wv=t>>6;
    const int m=lane&15, kg=lane>>4;
    const int n0=wv*128;
    f32x4 acc[4][8];
#pragma unroll
    for (int nt=0;nt<8;nt++){
        float bi=b2a[n0+nt*16+m];
        f32x4 vv={bi,bi,bi,bi};
#pragma unroll
        for (int mt=0;mt<4;mt++) acc[mt][nt]=vv;
    }
#pragma unroll 2
    for (int ks=0;ks<16;ks++){
        s16x8 a[4],b[8];
#pragma unroll
        for (int mt=0;mt<4;mt++) a[mt]=*(const s16x8*)&at[mt*16+m][ks*32+kg*8];
#pragma unroll
        for (int nt=0;nt<8;nt++) b[nt]=*(const s16x8*)&w2aT[(size_t)(n0+nt*16+m)*512 + ks*32+kg*8];
#pragma unroll
        for (int mt=0;mt<4;mt++)
#pragma unroll
            for (int nt=0;nt<8;nt++)
                acc[mt][nt]=__builtin_amdgcn_mfma_f32_16x16x32_bf16(a[mt],b[nt],acc[mt][nt],0,0,0);
    }
#pragma unroll
    for (int nt=0;nt<8;nt++){
        const int n=n0+nt*16+m;
        const float rs=1.0f/__fsqrt_rn(__fadd_rn(var2[n],1e-5f));
        const float mu=mu2[n], gg=g2[n], bb=be2[n];
#pragma unroll
        for (int mt=0;mt<4;mt++){
#pragma unroll
            for (int rg=0;rg<4;rg++){
                float v=acc[mt][nt][rg];
                v=__fadd_rn(__fmul_rn(__fmul_rn(__fsub_rn(v,mu),rs),gg),bb);
                v=fmaxf(v,0.0f);
                const int lr=br+mt*16+kg*4+rg;
                gbuf[(size_t)lr*512+n]=f2bf(v);
            }
        }
    }
}

// ---------------- MLP3: g @ w2b + b2b -> per-seed max over 32 rows -> out --
// NOTE: d_out is float32 (reference output dtype).
__global__ __launch_bounds__(256,2) void mlp3_kernel(const unsigned short* __restrict__ gbuf,
    const unsigned short* __restrict__ w2bT, const float* __restrict__ b2b,
    float* __restrict__ outp, int rowBase){
    __shared__ __align__(16) unsigned short at[64][520];
    const int t=threadIdx.x;
    const int br=blockIdx.x*64;
    {
        const int lr=t>>2,q=t&3;
        const s16x8* src=(const s16x8*)&gbuf[((size_t)(br+lr))*512+q*128];
        s16x8* dst=(s16x8*)&at[lr][q*128];
#pragma unroll
        for (int u=0;u<16;u++) dst[u]=src[u];
    }
    __syncthreads();
    const int lane=t&63, wv=t>>6;
    const int m=lane&15, kg=lane>>4;
    const int n0=wv*96;
    f32x4 acc[4][6];
#pragma unroll
    for (int nt=0;nt<6;nt++){
        float bi=b2b[n0+nt*16+m];
        f32x4 vv={bi,bi,bi,bi};
#pragma unroll
        for (int mt=0;mt<4;mt++) acc[mt][nt]=vv;
    }
#pragma unroll 2
    for (int ks=0;ks<16;ks++){
        s16x8 a[4],b[6];
#pragma unroll
        for (int mt=0;mt<4;mt++) a[mt]=*(const s16x8*)&at[mt*16+m][ks*32+kg*8];
#pragma unroll
        for (int nt=0;nt<6;nt++) b[nt]=*(const s16x8*)&w2bT[(size_t)(n0+nt*16+m)*512+ks*32+kg*8];
#pragma unroll
        for (int mt=0;mt<4;mt++)
#pragma unroll
            for (int nt=0;nt<6;nt++)
                acc[mt][nt]=__builtin_amdgcn_mfma_f32_16x16x32_bf16(a[mt],b[nt],acc[mt][nt],0,0,0);
    }
    const int sA=(rowBase+br)>>5;
#pragma unroll
    for (int nt=0;nt<6;nt++){
        float pA=-__builtin_inff(), pB=-__builtin_inff();
#pragma unroll
        for (int mt=0;mt<4;mt++){
#pragma unroll
            for (int rg=0;rg<4;rg++){
                float v=acc[mt][nt][rg];
                if (mt<2) pA=fmaxf(pA,v); else pB=fmaxf(pB,v);
            }
        }
        pA=fmaxf(pA,__shfl_xor(pA,16)); pA=fmaxf(pA,__shfl_xor(pA,32));
        pB=fmaxf(pB,__shfl_xor(pB,16)); pB=fmaxf(pB,__shfl_xor(pB,32));
        if (lane<16){
            outp[(size_t)sA*384 + n0+nt*16+m]=pA;
            outp[(size_t)(sA+1)*384 + n0+nt*16+m]=pB;
        }
    }
}

extern "C" void kernel_launch(void* const* d_in, const int* in_sizes, int n_in,
                              void* d_out, int out_size, void* d_ws, size_t ws_size,
                              hipStream_t stream) {
    const float* pos =(const float*)d_in[0];
    // d_in[1] = batch (int64), unused (single graph)
    const float* w1a =(const float*)d_in[2];
    const float* b1a =(const float*)d_in[3];
    const float* g1  =(const float*)d_in[4];
    const float* be1 =(const float*)d_in[5];
    const float* mu1 =(const float*)d_in[6];
    const float* var1=(const float*)d_in[7];
    const float* w1b =(const float*)d_in[8];
    const float* b1b =(const float*)d_in[9];
    const float* w2a =(const float*)d_in[10];
    const float* b2a =(const float*)d_in[11];
    const float* g2  =(const float*)d_in[12];
    const float* be2 =(const float*)d_in[13];
    const float* mu2 =(const float*)d_in[14];
    const float* var2=(const float*)d_in[15];
    const float* w2b =(const float*)d_in[16];
    const float* b2b =(const float*)d_in[17];

    char* base=(char*)d_ws;
    size_t off=0;
    auto alloc=[&](size_t bytes)->void*{
        void* p=base+off; off=(off+bytes+255)&~(size_t)255; return p;
    };
    int*   seed_idx=(int*)  alloc((size_t)NSEED*4);
    float* seeds   =(float*)alloc((size_t)NSEED*3*4);
    float* pp      =(float*)alloc((size_t)NPTS*4);
    float* rel     =(float*)alloc((size_t)TOTROWS*3*4);
    unsigned short* hmaxb=(unsigned short*)alloc((size_t)NSEED*256*2);
    unsigned short* w1bT =(unsigned short*)alloc((size_t)256*128*2);
    unsigned short* w2aT =(unsigned short*)alloc((size_t)512*512*2);
    unsigned short* w2bT =(unsigned short*)alloc((size_t)384*512*2);
    size_t fixed=off;

    // pick the fewest chunks whose h/g scratch fits ws_size
    int nch=512;
    for (int c=1;c<=512;c*=2){
        size_t need=fixed + (size_t)(TOTROWS/c)*(256*2 + 512*2) + 1024;
        if (need<=ws_size){ nch=c; break; }
    }
    const int chunkRows=TOTROWS/nch;            // multiple of 256 for c<=512
    unsigned short* hbuf=(unsigned short*)alloc((size_t)chunkRows*256*2);
    unsigned short* gbuf=(unsigned short*)alloc((size_t)chunkRows*512*2);

    prep_kernel<<<256,256,0,stream>>>(pos,w1b,w2a,w2b,pp,w1bT,w2aT,w2bT);
    fps_kernel<<<1,FPS_T,0,stream>>>(pos,seed_idx,seeds);
    knn_kernel<<<NSEED/4,256,0,stream>>>(pos,pp,seeds,rel);
    for (int c=0;c<nch;c++){
        const int rowBase=c*chunkRows;
        mlp1_kernel<<<chunkRows/256,256,0,stream>>>(rel,w1a,b1a,g1,be1,mu1,var1,w1bT,b1b,hbuf,hmaxb,rowBase);
        mlp2_kernel<<<chunkRows/64,256,0,stream>>>(hbuf,hmaxb,w2aT,b2a,g2,be2,mu2,var2,gbuf,rowBase);
        mlp3_kernel<<<chunkRows/64,256,0,stream>>>(gbuf,w2bT,b2b,(float*)d_out,rowBase);
    }
}